// Round 8
// baseline (112.437 us; speedup 1.0000x reference)
//
#include <hip/hip_runtime.h>
#include <hip/hip_bf16.h>
#include <cstdint>
#include <cstddef>

#define TOKENS 8192
#define IN_F   1024
#define OUT_F  1024
#define ROWB   7168          // row stride bytes: 5120 i8 (P1..P5) + 2048 bf16 (silu)
#define BUF    16384         // LDS buffer: A 128x64B (8KB) + B 128x64B (8KB)

typedef __attribute__((ext_vector_type(4))) float          f32x4;
typedef __attribute__((ext_vector_type(4))) float          float4v;
typedef __attribute__((ext_vector_type(4))) int            i32x4;
typedef __attribute__((ext_vector_type(8))) __bf16         bf16x8;
typedef __attribute__((ext_vector_type(8))) unsigned short ushort8;
typedef __attribute__((ext_vector_type(8))) char           char8;

__device__ __forceinline__ unsigned short f2bf(float f) {
    unsigned int u = __builtin_bit_cast(unsigned int, f);
    u += 0x7FFFu + ((u >> 16) & 1u);
    return (unsigned short)(u >> 16);
}

// ============================================================================
// Kernel 1: activations -> interleaved rows Arow[b][0..5119]=P1..P5 i8 (x63.5),
//           Arow[b][5120..7167] = silu bf16.
// ============================================================================
__global__ __launch_bounds__(256) void act_kernel(const float* __restrict__ x,
                                                  char* __restrict__ Arow) {
    int gid = blockIdx.x * 256 + threadIdx.x;
    int b   = gid >> 7;
    int i8  = (gid & 127) << 3;

    const float* xp = x + (size_t)b * IN_F + i8;
    float xs[8];
    *(float4v*)&xs[0] = *(const float4v*)xp;
    *(float4v*)&xs[4] = *(const float4v*)(xp + 4);

    unsigned short sres[8];
    char8 q[5];
    #pragma unroll
    for (int e = 0; e < 8; ++e) {
        float v  = xs[e];
        float s  = v / (1.f + __expf(-v));
        float t  = tanhf(v);
        float p1 = 2.f * t;
        float p2 = (12.f / 24.f) * t * p1 - (8.f / 24.f) * 1.f;
        float p3 = (64.f / 120.f) * t * p2 - (48.f / 120.f) * p1;
        float p4 = (180.f / 336.f) * t * p3 - (144.f / 336.f) * p2;
        float p5 = (384.f / 720.f) * t * p4 - (320.f / 720.f) * p3;
        sres[e] = f2bf(s);
        q[0][e] = (char)__float2int_rn(p1 * 63.5f);
        q[1][e] = (char)__float2int_rn(p2 * 63.5f);
        q[2][e] = (char)__float2int_rn(p3 * 63.5f);
        q[3][e] = (char)__float2int_rn(p4 * 63.5f);
        q[4][e] = (char)__float2int_rn(p5 * 63.5f);
    }
    char* row = Arow + (size_t)b * ROWB;
    #pragma unroll
    for (int k = 0; k < 5; ++k)
        *(char8*)(row + k * 1024 + i8) = q[k];
    *(ushort8*)(row + 5120 + i8 * 2) = *(const ushort8*)&sres[0];
}

// ============================================================================
// Kernel 2: weights -> Brow[o][0..5119]=C1..C5 i8 (per-row scale),
//           Brow[o][5120..7167]=W bf16; scaleC[o]; bias + C0-fold -> bias_aug.
// ============================================================================
__global__ __launch_bounds__(256) void wt_kernel(const float* __restrict__ W,
                                                 const float* __restrict__ C,
                                                 const float* __restrict__ bias,
                                                 char* __restrict__ Brow,
                                                 float* __restrict__ scaleC,
                                                 float* __restrict__ bias_aug) {
    int o   = blockIdx.x;
    int tid = threadIdx.x;
    char* row = Brow + (size_t)o * ROWB;
    float cv[4][5];
    float biasacc = 0.f, amax = 0.f;
    #pragma unroll
    for (int j = 0; j < 4; ++j) {
        int i = tid + j * 256;
        *(unsigned short*)(row + 5120 + i * 2) = f2bf(W[(size_t)o * IN_F + i]);
        const float* c = C + ((size_t)o * IN_F + i) * 6;
        biasacc += c[0];
        #pragma unroll
        for (int k = 0; k < 5; ++k) {
            float v = c[k + 1];
            cv[j][k] = v;
            amax = fmaxf(amax, fabsf(v));
        }
    }
    #pragma unroll
    for (int off = 32; off > 0; off >>= 1) {
        biasacc += __shfl_down(biasacc, off, 64);
        amax = fmaxf(amax, __shfl_down(amax, off, 64));
    }
    __shared__ float redS[4], redM[4];
    int lane = tid & 63, wv = tid >> 6;
    if (lane == 0) { redS[wv] = biasacc; redM[wv] = amax; }
    __syncthreads();
    float rA = fmaxf(fmaxf(redM[0], redM[1]), fmaxf(redM[2], redM[3]));
    rA = fmaxf(rA, 1e-20f);
    float rinv = 127.f / rA;
    if (tid == 0) {
        scaleC[o]   = rA / 127.f;
        bias_aug[o] = bias[o] + redS[0] + redS[1] + redS[2] + redS[3];
    }
    #pragma unroll
    for (int j = 0; j < 4; ++j) {
        int i = tid + j * 256;
        #pragma unroll
        for (int k = 0; k < 5; ++k)
            row[k * 1024 + i] = (char)__float2int_rn(cv[j][k] * rinv);
    }
}

// ============================================================================
// Kernel 3: fused GEMM, 128x128 tile, 256 thr (4 waves, wave-tile 64x64),
//   grid 512 = 2 blocks/CU (8 waves/CU). Tiles S=0..111 read row bytes
//   [S*64, S*64+64): S<80 i8 (mfma_i32_16x16x64_i8), S>=80 bf16
//   (mfma_f32_16x16x32_bf16) — identical LDS geometry both segments.
//   LDS 64KB = 4 bufs x [A 128x64B | B 128x64B], zero-conflict XOR swizzle.
//   Per tile T: stage T+3 | vmcnt(8) | BAR | rd frags(T+1) | lgkm(8) |
//               16 MFMA | BAR.   (buf reuse proven by lgkm@T-1 + end barrier)
// ============================================================================
__global__ __launch_bounds__(256, 2) void gemm_kernel(
    const char* __restrict__ Arow,
    const char* __restrict__ Brow,
    const float* __restrict__ scaleC,
    const float* __restrict__ bias_aug,
    float* __restrict__ out)
{
    __shared__ __align__(16) char ldsc[65536];   // 64 KB

    const int tid  = threadIdx.x;
    const int lane = tid & 63;
    const int wave = tid >> 6;              // 0..3
    const int wr   = wave >> 1;             // 0..1 (M)
    const int wc   = wave & 1;              // 0..1 (N)
    const int fr   = lane & 15;
    const int fg   = lane >> 4;
    const int wrbase = wr * 64;
    const int wcbase = wc * 64;

    const int bn = blockIdx.x & 7;          // XCD-local B panel
    const int bm = blockIdx.x >> 3;         // 0..63

    // staging: dest linear tid*16 per 4KB chunk (64 rows x 64B);
    // dest row r = chunk*64 + (tid>>2), slot tid&3;
    // source slot = (tid&3) ^ ((r>>1)&3) = (tid&3) ^ ((tid>>3)&3).
    const int r0   = tid >> 2;
    const int sswz = ((tid & 3) ^ ((tid >> 3) & 3)) << 4;
    const char* gA = Arow + (size_t)(bm * 128 + r0) * ROWB + sswz;
    const char* gB = Brow + (size_t)(bn * 128 + r0) * ROWB + sswz;

    // ds_read swizzled slot within 64B row ((row>>1)&3 == (fr>>1)&3)
    const int kcs = (fg << 4) ^ (((fr >> 1) & 3) << 4);

    i32x4 accI[4][4] = {};
    f32x4 accF[4][4];
    i32x4 xa[4], xb[4], ya[4], yb[4];

    float sc_[4];
    #pragma unroll
    for (int ni = 0; ni < 4; ++ni)
        sc_[ni] = scaleC[bn * 128 + wcbase + ni * 16 + fr] * (1.f / 63.5f);

#define GLDS(SRC, DST) __builtin_amdgcn_global_load_lds(                        \
    (const __attribute__((address_space(1))) void*)(SRC),                       \
    (__attribute__((address_space(3))) void*)(DST), 16, 0, 0)

#define STAGE(S, BO) do {                                                       \
    const size_t _ko = (size_t)(S) * 64;                                        \
    GLDS(gA + _ko,                      ldsc + (BO) + tid * 16);                \
    GLDS(gA + (size_t)64 * ROWB + _ko,  ldsc + (BO) + 4096 + tid * 16);         \
    GLDS(gB + _ko,                      ldsc + (BO) + 8192 + tid * 16);         \
    GLDS(gB + (size_t)64 * ROWB + _ko,  ldsc + (BO) + 12288 + tid * 16);        \
} while (0)

#define RD(DA, DB, BO) do {                                                     \
    _Pragma("unroll")                                                           \
    for (int i_ = 0; i_ < 4; ++i_)                                              \
        DA[i_] = *(const i32x4*)(ldsc + (BO) + (wrbase + i_ * 16 + fr) * 64 + kcs); \
    _Pragma("unroll")                                                           \
    for (int i_ = 0; i_ < 4; ++i_)                                              \
        DB[i_] = *(const i32x4*)(ldsc + (BO) + 8192 + (wcbase + i_ * 16 + fr) * 64 + kcs); \
} while (0)

#define MFI(CA, CB) do { __builtin_amdgcn_s_setprio(1);                         \
    _Pragma("unroll")                                                           \
    for (int mi_ = 0; mi_ < 4; ++mi_)                                           \
        _Pragma("unroll")                                                       \
        for (int ni_ = 0; ni_ < 4; ++ni_)                                       \
            accI[mi_][ni_] = __builtin_amdgcn_mfma_i32_16x16x64_i8(             \
                CA[mi_], CB[ni_], accI[mi_][ni_], 0, 0, 0);                     \
    __builtin_amdgcn_s_setprio(0); } while (0)

#define MFF(CA, CB) do { __builtin_amdgcn_s_setprio(1);                         \
    _Pragma("unroll")                                                           \
    for (int mi_ = 0; mi_ < 4; ++mi_)                                           \
        _Pragma("unroll")                                                       \
        for (int ni_ = 0; ni_ < 4; ++ni_)                                       \
            accF[mi_][ni_] = __builtin_amdgcn_mfma_f32_16x16x32_bf16(           \
                __builtin_bit_cast(bf16x8, CA[mi_]),                            \
                __builtin_bit_cast(bf16x8, CB[ni_]),                            \
                accF[mi_][ni_], 0, 0, 0);                                       \
    __builtin_amdgcn_s_setprio(0); } while (0)

#define TILE(T, BR, BS, MF, CA, CB, NA, NB, DOST, RDN, CNT, LG) do {            \
    if (DOST) STAGE((T) + 3, (BS));                                             \
    asm volatile("s_waitcnt vmcnt(" #CNT ")" ::: "memory");                     \
    __builtin_amdgcn_s_barrier();                                               \
    if (RDN) RD(NA, NB, (BR));                                                  \
    asm volatile("s_waitcnt lgkmcnt(" #LG ")" ::: "memory");                    \
    __builtin_amdgcn_sched_barrier(0);                                          \
    MF(CA, CB);                                                                 \
    __builtin_amdgcn_s_barrier();                                               \
} while (0)

    // prologue: stage tiles 0,1,2; tile-0 landed (forces to 8 of 12),
    // barrier for cross-wave visibility, pre-read tile-0 frags.
    STAGE(0, 0 * BUF);
    STAGE(1, 1 * BUF);
    STAGE(2, 2 * BUF);
    asm volatile("s_waitcnt vmcnt(8)" ::: "memory");
    __builtin_amdgcn_s_barrier();
    RD(xa, xb, 0 * BUF);

    // i8 segment: tiles 0..79 (staging runs ahead into bf16 region — uniform)
    for (int t = 0; t < 80; t += 4) {
        TILE(t + 0, 1 * BUF, 3 * BUF, MFI, xa, xb, ya, yb, 1, 1, 8, 8);
        TILE(t + 1, 2 * BUF, 0 * BUF, MFI, ya, yb, xa, xb, 1, 1, 8, 8);
        TILE(t + 2, 3 * BUF, 1 * BUF, MFI, xa, xb, ya, yb, 1, 1, 8, 8);
        TILE(t + 3, 0 * BUF, 2 * BUF, MFI, ya, yb, xa, xb, 1, 1, 8, 8);
    }

    // dequantize: accF = accI * scaleC[col]/63.5
    #pragma unroll
    for (int mi = 0; mi < 4; ++mi)
        #pragma unroll
        for (int ni = 0; ni < 4; ++ni)
            #pragma unroll
            for (int rr = 0; rr < 4; ++rr)
                accF[mi][ni][rr] = (float)accI[mi][ni][rr] * sc_[ni];

    // bf16 segment: tiles 80..107
    for (int t = 80; t < 108; t += 4) {
        TILE(t + 0, 1 * BUF, 3 * BUF, MFF, xa, xb, ya, yb, 1, 1, 8, 8);
        TILE(t + 1, 2 * BUF, 0 * BUF, MFF, ya, yb, xa, xb, 1, 1, 8, 8);
        TILE(t + 2, 3 * BUF, 1 * BUF, MFF, xa, xb, ya, yb, 1, 1, 8, 8);
        TILE(t + 3, 0 * BUF, 2 * BUF, MFF, ya, yb, xa, xb, 1, 1, 8, 8);
    }
    // tail: 108 stages 111; 109/110 drain; 111 computes last frags
    TILE(108, 1 * BUF, 3 * BUF, MFF, xa, xb, ya, yb, 1, 1, 8, 8);
    TILE(109, 2 * BUF, 0 * BUF, MFF, ya, yb, xa, xb, 0, 1, 4, 8);
    TILE(110, 3 * BUF, 0 * BUF, MFF, xa, xb, ya, yb, 0, 1, 0, 8);
    TILE(111, 0 * BUF, 0 * BUF, MFF, ya, yb, xa, xb, 0, 0, 0, 0);

#undef TILE
#undef MFF
#undef MFI
#undef RD
#undef STAGE
#undef GLDS

    // epilogue: D row=(lane>>4)*4+reg, col=lane&15 ; + bias
    #pragma unroll
    for (int ni = 0; ni < 4; ++ni) {
        const int col = bn * 128 + wcbase + ni * 16 + fr;
        const float bv = bias_aug[col];
        #pragma unroll
        for (int mi = 0; mi < 4; ++mi) {
            #pragma unroll
            for (int rr = 0; rr < 4; ++rr) {
                const int row = bm * 128 + wrbase + mi * 16 + fg * 4 + rr;
                out[(size_t)row * OUT_F + col] = accF[mi][ni][rr] + bv;
            }
        }
    }
}

// ============================================================================
extern "C" void kernel_launch(void* const* d_in, const int* in_sizes, int n_in,
                              void* d_out, int out_size, void* d_ws, size_t ws_size,
                              hipStream_t stream) {
    const float* x    = (const float*)d_in[0];
    const float* W    = (const float*)d_in[1];
    const float* C    = (const float*)d_in[2];
    const float* bias = (const float*)d_in[3];
    float* out = (float*)d_out;

    char* ws = (char*)d_ws;
    char*  Arow     = ws;                               // 8192*7168 = 58,720,256
    char*  Brow     = ws + 58720256;                    // 1024*7168 =  7,340,032
    float* bias_aug = (float*)(ws + 66060288);          // 4 KB
    float* scaleC   = (float*)(ws + 66064384);          // 4 KB

    hipLaunchKernelGGL(act_kernel, dim3(TOKENS * IN_F / 8 / 256), dim3(256), 0, stream,
                       x, Arow);
    hipLaunchKernelGGL(wt_kernel, dim3(OUT_F), dim3(256), 0, stream,
                       W, C, bias, Brow, scaleC, bias_aug);
    hipLaunchKernelGGL(gemm_kernel, dim3(512), dim3(256), 0, stream,
                       Arow, Brow, scaleC, bias_aug, out);
}

// Round 9
// 103.912 us; speedup vs baseline: 1.0820x; 1.0820x over previous
//
#include <hip/hip_runtime.h>
#include <hip/hip_bf16.h>
#include <cstdint>
#include <cstddef>

#define TOKENS 8192
#define IN_F   1024
#define OUT_F  1024
#define ROWB   7168          // row stride bytes: 5120 i8 (P1..P5) + 2048 bf16 (silu)
#define BUF    16384         // LDS buffer: A 128x64B (8KB) + B 128x64B (8KB)

typedef __attribute__((ext_vector_type(4))) float          f32x4;
typedef __attribute__((ext_vector_type(4))) float          float4v;
typedef __attribute__((ext_vector_type(4))) int            i32x4;
typedef __attribute__((ext_vector_type(8))) __bf16         bf16x8;
typedef __attribute__((ext_vector_type(8))) unsigned short ushort8;
typedef __attribute__((ext_vector_type(8))) char           char8;

__device__ __forceinline__ unsigned short f2bf(float f) {
    unsigned int u = __builtin_bit_cast(unsigned int, f);
    u += 0x7FFFu + ((u >> 16) & 1u);
    return (unsigned short)(u >> 16);
}

// ============================================================================
// Kernel 1: activations -> interleaved rows Arow[b][0..5119]=P1..P5 i8 (x63.5),
//           Arow[b][5120..7167] = silu bf16.  Fast tanh via __expf.
// ============================================================================
__global__ __launch_bounds__(256) void act_kernel(const float* __restrict__ x,
                                                  char* __restrict__ Arow) {
    int gid = blockIdx.x * 256 + threadIdx.x;
    int b   = gid >> 7;
    int i8  = (gid & 127) << 3;

    const float* xp = x + (size_t)b * IN_F + i8;
    float xs[8];
    *(float4v*)&xs[0] = *(const float4v*)xp;
    *(float4v*)&xs[4] = *(const float4v*)(xp + 4);

    unsigned short sres[8];
    char8 q[5];
    #pragma unroll
    for (int e = 0; e < 8; ++e) {
        float v  = xs[e];
        float s  = v / (1.f + __expf(-v));
        float t  = 1.f - 2.f / (1.f + __expf(2.f * v));   // tanh(v), exact at +-inf
        float p1 = 2.f * t;
        float p2 = (12.f / 24.f) * t * p1 - (8.f / 24.f) * 1.f;
        float p3 = (64.f / 120.f) * t * p2 - (48.f / 120.f) * p1;
        float p4 = (180.f / 336.f) * t * p3 - (144.f / 336.f) * p2;
        float p5 = (384.f / 720.f) * t * p4 - (320.f / 720.f) * p3;
        sres[e] = f2bf(s);
        q[0][e] = (char)__float2int_rn(p1 * 63.5f);
        q[1][e] = (char)__float2int_rn(p2 * 63.5f);
        q[2][e] = (char)__float2int_rn(p3 * 63.5f);
        q[3][e] = (char)__float2int_rn(p4 * 63.5f);
        q[4][e] = (char)__float2int_rn(p5 * 63.5f);
    }
    char* row = Arow + (size_t)b * ROWB;
    #pragma unroll
    for (int k = 0; k < 5; ++k)
        *(char8*)(row + k * 1024 + i8) = q[k];
    *(ushort8*)(row + 5120 + i8 * 2) = *(const ushort8*)&sres[0];
}

// ============================================================================
// Kernel 2: weights -> Brow[o][0..5119]=C1..C5 i8 (per-row scale),
//           Brow[o][5120..7167]=W bf16; scaleC[o]; bias + C0-fold -> bias_aug.
// ============================================================================
__global__ __launch_bounds__(256) void wt_kernel(const float* __restrict__ W,
                                                 const float* __restrict__ C,
                                                 const float* __restrict__ bias,
                                                 char* __restrict__ Brow,
                                                 float* __restrict__ scaleC,
                                                 float* __restrict__ bias_aug) {
    int o   = blockIdx.x;
    int tid = threadIdx.x;
    char* row = Brow + (size_t)o * ROWB;
    float cv[4][5];
    float biasacc = 0.f, amax = 0.f;
    #pragma unroll
    for (int j = 0; j < 4; ++j) {
        int i = tid + j * 256;
        *(unsigned short*)(row + 5120 + i * 2) = f2bf(W[(size_t)o * IN_F + i]);
        const float* c = C + ((size_t)o * IN_F + i) * 6;
        biasacc += c[0];
        #pragma unroll
        for (int k = 0; k < 5; ++k) {
            float v = c[k + 1];
            cv[j][k] = v;
            amax = fmaxf(amax, fabsf(v));
        }
    }
    #pragma unroll
    for (int off = 32; off > 0; off >>= 1) {
        biasacc += __shfl_down(biasacc, off, 64);
        amax = fmaxf(amax, __shfl_down(amax, off, 64));
    }
    __shared__ float redS[4], redM[4];
    int lane = tid & 63, wv = tid >> 6;
    if (lane == 0) { redS[wv] = biasacc; redM[wv] = amax; }
    __syncthreads();
    float rA = fmaxf(fmaxf(redM[0], redM[1]), fmaxf(redM[2], redM[3]));
    rA = fmaxf(rA, 1e-20f);
    float rinv = 127.f / rA;
    if (tid == 0) {
        scaleC[o]   = rA / 127.f;
        bias_aug[o] = bias[o] + redS[0] + redS[1] + redS[2] + redS[3];
    }
    #pragma unroll
    for (int j = 0; j < 4; ++j) {
        int i = tid + j * 256;
        #pragma unroll
        for (int k = 0; k < 5; ++k)
            row[k * 1024 + i] = (char)__float2int_rn(cv[j][k] * rinv);
    }
}

// ============================================================================
// Kernel 3: fused GEMM, 128x128 tile, 256 thr (4 waves, wave-tile 64x64),
//   grid 512 = 2 blocks/CU. XCD-local decode: each XCD owns 8 bm x all bn
//   (A fetched once chip-wide, B once per XCD; per-K-step L2 set = 128KB).
//   Tiles S=0..111: S<80 i8 (mfma_i32_16x16x64_i8), S>=80 bf16 — identical
//   LDS geometry. LDS 64KB = 4 bufs, zero-conflict XOR swizzle.
//   Per tile T: stage T+3 | vmcnt(8) | BAR | rd frags(T+1) | lgkm(8) |
//               16 MFMA | BAR.
// ============================================================================
__global__ __launch_bounds__(256, 2) void gemm_kernel(
    const char* __restrict__ Arow,
    const char* __restrict__ Brow,
    const float* __restrict__ scaleC,
    const float* __restrict__ bias_aug,
    float* __restrict__ out)
{
    __shared__ __align__(16) char ldsc[65536];   // 64 KB

    const int tid  = threadIdx.x;
    const int lane = tid & 63;
    const int wave = tid >> 6;              // 0..3
    const int wr   = wave >> 1;             // 0..1 (M)
    const int wc   = wave & 1;              // 0..1 (N)
    const int fr   = lane & 15;
    const int fg   = lane >> 4;
    const int wrbase = wr * 64;
    const int wcbase = wc * 64;

    // XCD-local decode: xcd = bid&7 under round-robin dispatch.
    // bm-sharing blocks (bn=0..7) stay on ONE xcd -> A panel fetched once.
    const int bm = (blockIdx.x & 7) * 8 + ((blockIdx.x >> 3) & 7);  // 0..63
    const int bn = blockIdx.x >> 6;                                  // 0..7

    // staging: dest linear tid*16 per 4KB chunk (64 rows x 64B);
    // dest row r = chunk*64 + (tid>>2), slot tid&3;
    // source slot = (tid&3) ^ ((r>>1)&3) = (tid&3) ^ ((tid>>3)&3).
    const int r0   = tid >> 2;
    const int sswz = ((tid & 3) ^ ((tid >> 3) & 3)) << 4;
    const char* gA = Arow + (size_t)(bm * 128 + r0) * ROWB + sswz;
    const char* gB = Brow + (size_t)(bn * 128 + r0) * ROWB + sswz;

    // ds_read swizzled slot within 64B row ((row>>1)&3 == (fr>>1)&3)
    const int kcs = (fg << 4) ^ (((fr >> 1) & 3) << 4);

    i32x4 accI[4][4] = {};
    f32x4 accF[4][4];
    i32x4 xa[4], xb[4], ya[4], yb[4];

    float sc_[4];
    #pragma unroll
    for (int ni = 0; ni < 4; ++ni)
        sc_[ni] = scaleC[bn * 128 + wcbase + ni * 16 + fr] * (1.f / 63.5f);

#define GLDS(SRC, DST) __builtin_amdgcn_global_load_lds(                        \
    (const __attribute__((address_space(1))) void*)(SRC),                       \
    (__attribute__((address_space(3))) void*)(DST), 16, 0, 0)

#define STAGE(S, BO) do {                                                       \
    const size_t _ko = (size_t)(S) * 64;                                        \
    GLDS(gA + _ko,                      ldsc + (BO) + tid * 16);                \
    GLDS(gA + (size_t)64 * ROWB + _ko,  ldsc + (BO) + 4096 + tid * 16);         \
    GLDS(gB + _ko,                      ldsc + (BO) + 8192 + tid * 16);         \
    GLDS(gB + (size_t)64 * ROWB + _ko,  ldsc + (BO) + 12288 + tid * 16);        \
} while (0)

#define RD(DA, DB, BO) do {                                                     \
    _Pragma("unroll")                                                           \
    for (int i_ = 0; i_ < 4; ++i_)                                              \
        DA[i_] = *(const i32x4*)(ldsc + (BO) + (wrbase + i_ * 16 + fr) * 64 + kcs); \
    _Pragma("unroll")                                                           \
    for (int i_ = 0; i_ < 4; ++i_)                                              \
        DB[i_] = *(const i32x4*)(ldsc + (BO) + 8192 + (wcbase + i_ * 16 + fr) * 64 + kcs); \
} while (0)

#define MFI(CA, CB) do { __builtin_amdgcn_s_setprio(1);                         \
    _Pragma("unroll")                                                           \
    for (int mi_ = 0; mi_ < 4; ++mi_)                                           \
        _Pragma("unroll")                                                       \
        for (int ni_ = 0; ni_ < 4; ++ni_)                                       \
            accI[mi_][ni_] = __builtin_amdgcn_mfma_i32_16x16x64_i8(             \
                CA[mi_], CB[ni_], accI[mi_][ni_], 0, 0, 0);                     \
    __builtin_amdgcn_s_setprio(0); } while (0)

#define MFF(CA, CB) do { __builtin_amdgcn_s_setprio(1);                         \
    _Pragma("unroll")                                                           \
    for (int mi_ = 0; mi_ < 4; ++mi_)                                           \
        _Pragma("unroll")                                                       \
        for (int ni_ = 0; ni_ < 4; ++ni_)                                       \
            accF[mi_][ni_] = __builtin_amdgcn_mfma_f32_16x16x32_bf16(           \
                __builtin_bit_cast(bf16x8, CA[mi_]),                            \
                __builtin_bit_cast(bf16x8, CB[ni_]),                            \
                accF[mi_][ni_], 0, 0, 0);                                       \
    __builtin_amdgcn_s_setprio(0); } while (0)

#define TILE(T, BR, BS, MF, CA, CB, NA, NB, DOST, RDN, CNT, LG) do {            \
    if (DOST) STAGE((T) + 3, (BS));                                             \
    asm volatile("s_waitcnt vmcnt(" #CNT ")" ::: "memory");                     \
    __builtin_amdgcn_s_barrier();                                               \
    if (RDN) RD(NA, NB, (BR));                                                  \
    asm volatile("s_waitcnt lgkmcnt(" #LG ")" ::: "memory");                    \
    __builtin_amdgcn_sched_barrier(0);                                          \
    MF(CA, CB);                                                                 \
    __builtin_amdgcn_s_barrier();                                               \
} while (0)

    // prologue: stage tiles 0,1,2; tile-0 landed, barrier, pre-read tile-0.
    STAGE(0, 0 * BUF);
    STAGE(1, 1 * BUF);
    STAGE(2, 2 * BUF);
    asm volatile("s_waitcnt vmcnt(8)" ::: "memory");
    __builtin_amdgcn_s_barrier();
    RD(xa, xb, 0 * BUF);

    // i8 segment: tiles 0..79 (staging runs ahead into bf16 region — uniform)
    for (int t = 0; t < 80; t += 4) {
        TILE(t + 0, 1 * BUF, 3 * BUF, MFI, xa, xb, ya, yb, 1, 1, 8, 8);
        TILE(t + 1, 2 * BUF, 0 * BUF, MFI, ya, yb, xa, xb, 1, 1, 8, 8);
        TILE(t + 2, 3 * BUF, 1 * BUF, MFI, xa, xb, ya, yb, 1, 1, 8, 8);
        TILE(t + 3, 0 * BUF, 2 * BUF, MFI, ya, yb, xa, xb, 1, 1, 8, 8);
    }

    // dequantize: accF = accI * scaleC[col]/63.5
    #pragma unroll
    for (int mi = 0; mi < 4; ++mi)
        #pragma unroll
        for (int ni = 0; ni < 4; ++ni)
            #pragma unroll
            for (int rr = 0; rr < 4; ++rr)
                accF[mi][ni][rr] = (float)accI[mi][ni][rr] * sc_[ni];

    // bf16 segment: tiles 80..107
    for (int t = 80; t < 108; t += 4) {
        TILE(t + 0, 1 * BUF, 3 * BUF, MFF, xa, xb, ya, yb, 1, 1, 8, 8);
        TILE(t + 1, 2 * BUF, 0 * BUF, MFF, ya, yb, xa, xb, 1, 1, 8, 8);
        TILE(t + 2, 3 * BUF, 1 * BUF, MFF, xa, xb, ya, yb, 1, 1, 8, 8);
        TILE(t + 3, 0 * BUF, 2 * BUF, MFF, ya, yb, xa, xb, 1, 1, 8, 8);
    }
    // tail: 108 stages 111; 109/110 drain; 111 computes last frags
    TILE(108, 1 * BUF, 3 * BUF, MFF, xa, xb, ya, yb, 1, 1, 8, 8);
    TILE(109, 2 * BUF, 0 * BUF, MFF, ya, yb, xa, xb, 0, 1, 4, 8);
    TILE(110, 3 * BUF, 0 * BUF, MFF, xa, xb, ya, yb, 0, 1, 0, 8);
    TILE(111, 0 * BUF, 0 * BUF, MFF, ya, yb, xa, xb, 0, 0, 0, 0);

#undef TILE
#undef MFF
#undef MFI
#undef RD
#undef STAGE
#undef GLDS

    // epilogue: D row=(lane>>4)*4+reg, col=lane&15 ; + bias
    #pragma unroll
    for (int ni = 0; ni < 4; ++ni) {
        const int col = bn * 128 + wcbase + ni * 16 + fr;
        const float bv = bias_aug[col];
        #pragma unroll
        for (int mi = 0; mi < 4; ++mi) {
            #pragma unroll
            for (int rr = 0; rr < 4; ++rr) {
                const int row = bm * 128 + wrbase + mi * 16 + fg * 4 + rr;
                out[(size_t)row * OUT_F + col] = accF[mi][ni][rr] + bv;
            }
        }
    }
}

// ============================================================================
extern "C" void kernel_launch(void* const* d_in, const int* in_sizes, int n_in,
                              void* d_out, int out_size, void* d_ws, size_t ws_size,
                              hipStream_t stream) {
    const float* x    = (const float*)d_in[0];
    const float* W    = (const float*)d_in[1];
    const float* C    = (const float*)d_in[2];
    const float* bias = (const float*)d_in[3];
    float* out = (float*)d_out;

    char* ws = (char*)d_ws;
    char*  Arow     = ws;                               // 8192*7168 = 58,720,256
    char*  Brow     = ws + 58720256;                    // 1024*7168 =  7,340,032
    float* bias_aug = (float*)(ws + 66060288);          // 4 KB
    float* scaleC   = (float*)(ws + 66064384);          // 4 KB

    hipLaunchKernelGGL(act_kernel, dim3(TOKENS * IN_F / 8 / 256), dim3(256), 0, stream,
                       x, Arow);
    hipLaunchKernelGGL(wt_kernel, dim3(OUT_F), dim3(256), 0, stream,
                       W, C, bias, Brow, scaleC, bias_aug);
    hipLaunchKernelGGL(gemm_kernel, dim3(512), dim3(256), 0, stream,
                       Arow, Brow, scaleC, bias_aug, out);
}